// Round 2
// baseline (1998.567 us; speedup 1.0000x reference)
//
#include <hip/hip_runtime.h>

// Att_RNN_GRU: B=128, T=1024, I=128, H=256 (3H=768), A=40
// Phase 1: gx = x @ W_ih^T + b_ih              -> f16 [B*T, 768]   (tiled fp32 GEMM)
// Phase 2: GRU recurrence, 1 block per batch; h_t overwrites gx row (b,t)[0:256]
//          W_hh register-resident as packed f16, v_dot2_f32_f16 dots, fp32 h state
// Phase 3a: s[b,t] = wu . tanh(wv_W @ out + wv_b)   (outs = gx rows, stride 768)
// Phase 3b: softmax over t, context, out = context @ h2o_W^T + b
//
// Workspace (must stay < 256 MiB — round-1 layout was 269.4 MB and aborted):
//   s   @ 0        :   524,288 B
//   Wp  @ 524288   :   393,216 B
//   gx  @ 917504   : 201,326,592 B     total 202,244,096 B

#define B_ 128
#define T_ 1024
#define I_ 128
#define H_ 256
#define G_ 768
#define A_ 40

typedef _Float16 f16;
typedef _Float16 f16x2 __attribute__((ext_vector_type(2)));

__device__ __forceinline__ float fdot2(unsigned a, unsigned b, float c){
#if __has_builtin(__builtin_amdgcn_fdot2)
  return __builtin_amdgcn_fdot2(__builtin_bit_cast(f16x2, a),
                                __builtin_bit_cast(f16x2, b), c, false);
#else
  f16x2 av = __builtin_bit_cast(f16x2, a), bv = __builtin_bit_cast(f16x2, b);
  return c + (float)av.x * (float)bv.x + (float)av.y * (float)bv.y;
#endif
}

__device__ __forceinline__ float2 h2f(unsigned u){
  f16x2 h = __builtin_bit_cast(f16x2, u);
  return make_float2((float)h.x, (float)h.y);
}
__device__ __forceinline__ unsigned f2h2(float a, float b){
  f16x2 h; h.x = (f16)a; h.y = (f16)b;
  return __builtin_bit_cast(unsigned, h);
}
__device__ __forceinline__ float sigm_(float x){ return 1.f / (1.f + __expf(-x)); }
__device__ __forceinline__ float tanh_(float x){ return 1.f - 2.f / (__expf(2.f * x) + 1.f); }

// ---------------------------------------------------------------- prep W_hh
// Repack W_hh fp32 [768][256] -> packed f16 dwords so the recurrent kernel's
// thread `tid` (of 512) loads w[d] = Wp[d*512 + tid] coalesced.
// Thread (g=tid>>1, sub=tid&1) owns rows {g, g+256, g+512}, k-half sub.
__global__ __launch_bounds__(256) void k_prep_w(const float* __restrict__ W,
                                                unsigned* __restrict__ Wp){
  int idx = blockIdx.x * 256 + threadIdx.x;      // 0 .. 98303
  int d   = idx >> 9;                            // 0..191
  int col = idx & 511;                           // destination thread id
  int g = col >> 1, sub = col & 1;
  int c = d >> 6, p = d & 63;                    // row-slot, k-pair index
  int r = g + 256 * c;
  int k = sub * 128 + 2 * p;
  Wp[(size_t)d * 512 + col] = f2h2(W[r * 256 + k], W[r * 256 + k + 1]);
}

// ---------------------------------------------------------------- phase 1
// gx[m][n] = sum_k x[m][k]*W_ih[n][k] + b_ih[n], stored packed f16.
// 64x64 tile, K staged in 2 halves of 64.
__global__ __launch_bounds__(256) void k_gx(const float* __restrict__ x,
                                            const float* __restrict__ wih,
                                            const float* __restrict__ bih,
                                            unsigned* __restrict__ gx){
  __shared__ float Al[64 * 68];   // [k][row]
  __shared__ float Bl[64 * 68];
  const int tid = threadIdx.x;
  const int m0 = blockIdx.x * 64, n0 = blockIdx.y * 64;
  const int ar = tid >> 4, bc = tid & 15;
  float acc[4][4] = {{0.f}};

  for (int kh = 0; kh < 2; ++kh){
    __syncthreads();
    #pragma unroll
    for (int u = 0; u < 4; ++u){
      int idx = tid + 256 * u;
      int row = idx >> 4;         // 0..63
      int kq  = idx & 15;         // 0..15
      float4 va = *(const float4*)(x   + (size_t)(m0 + row) * I_ + kh * 64 + kq * 4);
      float4 vb = *(const float4*)(wih + (size_t)(n0 + row) * I_ + kh * 64 + kq * 4);
      Al[(kq*4+0)*68 + row] = va.x; Al[(kq*4+1)*68 + row] = va.y;
      Al[(kq*4+2)*68 + row] = va.z; Al[(kq*4+3)*68 + row] = va.w;
      Bl[(kq*4+0)*68 + row] = vb.x; Bl[(kq*4+1)*68 + row] = vb.y;
      Bl[(kq*4+2)*68 + row] = vb.z; Bl[(kq*4+3)*68 + row] = vb.w;
    }
    __syncthreads();
    for (int k = 0; k < 64; ++k){
      float4 a4 = *(const float4*)(Al + k * 68 + ar * 4);
      float4 b4 = *(const float4*)(Bl + k * 68 + bc * 4);
      acc[0][0] += a4.x*b4.x; acc[0][1] += a4.x*b4.y; acc[0][2] += a4.x*b4.z; acc[0][3] += a4.x*b4.w;
      acc[1][0] += a4.y*b4.x; acc[1][1] += a4.y*b4.y; acc[1][2] += a4.y*b4.z; acc[1][3] += a4.y*b4.w;
      acc[2][0] += a4.z*b4.x; acc[2][1] += a4.z*b4.y; acc[2][2] += a4.z*b4.z; acc[2][3] += a4.z*b4.w;
      acc[3][0] += a4.w*b4.x; acc[3][1] += a4.w*b4.y; acc[3][2] += a4.w*b4.z; acc[3][3] += a4.w*b4.w;
    }
  }

  float bn[4];
  #pragma unroll
  for (int j = 0; j < 4; ++j) bn[j] = bih[n0 + bc * 4 + j];
  #pragma unroll
  for (int i = 0; i < 4; ++i){
    int m = m0 + ar * 4 + i;
    uint2 st;
    st.x = f2h2(acc[i][0] + bn[0], acc[i][1] + bn[1]);
    st.y = f2h2(acc[i][2] + bn[2], acc[i][3] + bn[3]);
    *(uint2*)(gx + (size_t)m * (G_ / 2) + n0 / 2 + bc * 2) = st;
  }
}

// ---------------------------------------------------------------- phase 2
// One block per batch. 512 threads; thread pair (g, sub) computes gate rows
// {g, g+256, g+512} over k-half `sub`. W_hh f16 register-resident (192 dwords).
// h state: fp32 in sub==0 registers; packed f16 double-buffered in LDS.
// h_t (f16) is written into gx row (b,t)[0:256] — that row was fully consumed
// by step t-1's prefetch and the end-of-step barrier orders read -> write.
__global__ __launch_bounds__(512, 2) void k_gru(const unsigned* __restrict__ Wp,
                                                unsigned* __restrict__ gx,
                                                const float* __restrict__ bhh,
                                                int unused){
  __shared__ uint4 HB4[2][32];    // [buf][256 halfs]
  const int tid = threadIdx.x;
  const int b = blockIdx.x;
  const int g = tid >> 1, sub = tid & 1;

  unsigned w[192];
  #pragma unroll
  for (int d = 0; d < 192; ++d) w[d] = Wp[d * 512 + tid];

  float br = 0.f, bz = 0.f, bn_ = 0.f, hprev = 0.f;
  if (sub == 0){ br = bhh[g]; bz = bhh[H_ + g]; bn_ = bhh[2 * H_ + g]; }
  if (tid < 32) HB4[0][tid] = make_uint4(0, 0, 0, 0);
  __syncthreads();

  f16* gxp = (f16*)gx + (size_t)b * T_ * G_;

  float xr = 0.f, xz = 0.f, xn = 0.f;
  if (sub == 0){ xr = (float)gxp[g]; xz = (float)gxp[H_ + g]; xn = (float)gxp[2 * H_ + g]; }

  int buf = 0;
  for (int t = 0; t < T_; ++t){
    // prefetch next step's gx (hides HBM latency under the dots)
    float nr = 0.f, nz = 0.f, nn = 0.f;
    if (sub == 0 && t < T_ - 1){
      const f16* nx = gxp + (size_t)(t + 1) * G_;
      nr = (float)nx[g]; nz = (float)nx[H_ + g]; nn = (float)nx[2 * H_ + g];
    }

    float a0 = 0.f, a1 = 0.f, a2 = 0.f;
    #pragma unroll
    for (int i = 0; i < 16; ++i){
      uint4 hc = HB4[buf][sub * 16 + i];
      a0 = fdot2(w[      i*4+0], hc.x, a0); a0 = fdot2(w[      i*4+1], hc.y, a0);
      a0 = fdot2(w[      i*4+2], hc.z, a0); a0 = fdot2(w[      i*4+3], hc.w, a0);
      a1 = fdot2(w[ 64 + i*4+0], hc.x, a1); a1 = fdot2(w[ 64 + i*4+1], hc.y, a1);
      a1 = fdot2(w[ 64 + i*4+2], hc.z, a1); a1 = fdot2(w[ 64 + i*4+3], hc.w, a1);
      a2 = fdot2(w[128 + i*4+0], hc.x, a2); a2 = fdot2(w[128 + i*4+1], hc.y, a2);
      a2 = fdot2(w[128 + i*4+2], hc.z, a2); a2 = fdot2(w[128 + i*4+3], hc.w, a2);
    }
    a0 += __shfl_xor(a0, 1);
    a1 += __shfl_xor(a1, 1);
    a2 += __shfl_xor(a2, 1);

    if (sub == 0){
      float rg = sigm_(xr + a0 + br);
      float zg = sigm_(xz + a1 + bz);
      float ng = tanh_(xn + rg * (a2 + bn_));
      float hn = (1.f - zg) * ng + zg * hprev;
      hprev = hn;
      f16 hh = (f16)hn;
      ((f16*)HB4[buf ^ 1])[g] = hh;
      gxp[(size_t)t * G_ + g] = hh;   // overwrite consumed gx row with h_t
      xr = nr; xz = nz; xn = nn;
    }
    __syncthreads();
    buf ^= 1;
  }
}

// ---------------------------------------------------------------- phase 3a
// s[m] = sum_a wu[a] * tanh( sum_k outs[m][k]*wv_W[a][k] + wv_b[a] )
// outs = first 256 halfs of each 768-half gx row.
__global__ __launch_bounds__(256) void k_score(const f16* __restrict__ outs,
                                               const float* __restrict__ wvW,
                                               const float* __restrict__ wvb,
                                               const float* __restrict__ wu,
                                               float* __restrict__ s){
  __shared__ uint4 OT[32 * 33];      // 32 rows x 256 halfs, pad 33
  __shared__ float WV[A_ * 260];     // 40 x 256 fp32, pad 260
  const int tid = threadIdx.x;
  const int m0 = blockIdx.x * 32;

  #pragma unroll
  for (int u = 0; u < 4; ++u){
    int idx = tid + 256 * u;         // 0..1023
    int row = idx >> 5, col = idx & 31;
    OT[row * 33 + col] = *(const uint4*)(outs + (size_t)(m0 + row) * G_ + col * 8);
  }
  #pragma unroll
  for (int u = 0; u < 10; ++u){
    int f = tid + 256 * u;           // 0..2559 float4s
    int a = f >> 6, k4 = f & 63;
    float4 v = *(const float4*)(wvW + a * 256 + k4 * 4);
    *(float4*)(WV + a * 260 + k4 * 4) = v;
  }
  __syncthreads();

  const int m = tid >> 3, aq = tid & 7;
  float acc[5] = {0.f, 0.f, 0.f, 0.f, 0.f};
  for (int i = 0; i < 32; ++i){
    uint4 oc = OT[m * 33 + i];
    float2 o01 = h2f(oc.x), o23 = h2f(oc.y), o45 = h2f(oc.z), o67 = h2f(oc.w);
    #pragma unroll
    for (int sa = 0; sa < 5; ++sa){
      int a = aq + sa * 8;
      const float* wr = &WV[a * 260 + i * 8];
      float4 w0 = *(const float4*)wr;
      float4 w1 = *(const float4*)(wr + 4);
      acc[sa] += o01.x*w0.x + o01.y*w0.y + o23.x*w0.z + o23.y*w0.w
               + o45.x*w1.x + o45.y*w1.y + o67.x*w1.z + o67.y*w1.w;
    }
  }
  float sp = 0.f;
  #pragma unroll
  for (int sa = 0; sa < 5; ++sa){
    int a = aq + sa * 8;
    sp += wu[a] * tanh_(acc[sa] + wvb[a]);
  }
  sp += __shfl_xor(sp, 1);
  sp += __shfl_xor(sp, 2);
  sp += __shfl_xor(sp, 4);
  if (aq == 0) s[m0 + m] = sp;
}

// ---------------------------------------------------------------- phase 3b
// softmax over t per batch, context = sum_t alpha*outs, out[b] = context.h2o + b
__global__ __launch_bounds__(256) void k_ctx(const f16* __restrict__ outs,
                                             const float* __restrict__ s,
                                             const float* __restrict__ h2oW,
                                             const float* __restrict__ h2ob,
                                             float* __restrict__ out){
  __shared__ float AL[T_];
  __shared__ float red[8];
  const int tid = threadIdx.x;
  const int b = blockIdx.x;
  const float* sb = s + (size_t)b * T_;

  float v0 = sb[tid], v1 = sb[tid + 256], v2 = sb[tid + 512], v3 = sb[tid + 768];
  float mx = fmaxf(fmaxf(v0, v1), fmaxf(v2, v3));
  #pragma unroll
  for (int msk = 1; msk < 64; msk <<= 1) mx = fmaxf(mx, __shfl_xor(mx, msk));
  if ((tid & 63) == 0) red[tid >> 6] = mx;
  __syncthreads();
  mx = fmaxf(fmaxf(red[0], red[1]), fmaxf(red[2], red[3]));

  float e0 = __expf(v0 - mx), e1 = __expf(v1 - mx), e2 = __expf(v2 - mx), e3 = __expf(v3 - mx);
  float zs = e0 + e1 + e2 + e3;
  #pragma unroll
  for (int msk = 1; msk < 64; msk <<= 1) zs += __shfl_xor(zs, msk);
  if ((tid & 63) == 0) red[4 + (tid >> 6)] = zs;
  __syncthreads();
  float invZ = 1.f / (red[4] + red[5] + red[6] + red[7]);
  AL[tid] = e0 * invZ; AL[tid + 256] = e1 * invZ;
  AL[tid + 512] = e2 * invZ; AL[tid + 768] = e3 * invZ;
  __syncthreads();

  const f16* ob = outs + (size_t)b * T_ * G_;
  float acc = 0.f;
  for (int t = 0; t < T_; t += 4){
    acc += AL[t + 0] * (float)ob[(size_t)(t + 0) * G_ + tid];
    acc += AL[t + 1] * (float)ob[(size_t)(t + 1) * G_ + tid];
    acc += AL[t + 2] * (float)ob[(size_t)(t + 2) * G_ + tid];
    acc += AL[t + 3] * (float)ob[(size_t)(t + 3) * G_ + tid];
  }
  __syncthreads();
  float val = acc * h2oW[tid];
  #pragma unroll
  for (int msk = 1; msk < 64; msk <<= 1) val += __shfl_xor(val, msk);
  if ((tid & 63) == 0) red[tid >> 6] = val;
  __syncthreads();
  if (tid == 0) out[b] = red[0] + red[1] + red[2] + red[3] + h2ob[0];
}

// ---------------------------------------------------------------- launch
extern "C" void kernel_launch(void* const* d_in, const int* in_sizes, int n_in,
                              void* d_out, int out_size, void* d_ws, size_t ws_size,
                              hipStream_t stream){
  const float* x    = (const float*)d_in[0];
  const float* wih  = (const float*)d_in[1];
  const float* whh  = (const float*)d_in[2];
  const float* bih  = (const float*)d_in[3];
  const float* bhh  = (const float*)d_in[4];
  const float* wvW  = (const float*)d_in[5];
  const float* wvb  = (const float*)d_in[6];
  const float* wu   = (const float*)d_in[7];
  const float* h2oW = (const float*)d_in[8];
  const float* h2ob = (const float*)d_in[9];
  float* out = (float*)d_out;

  // workspace layout (202,244,096 B total — fits 256 MiB):
  char* ws = (char*)d_ws;
  float*    s  = (float*)ws;                      //     524,288 B
  unsigned* Wp = (unsigned*)(ws + 524288);        //     393,216 B
  unsigned* gx = (unsigned*)(ws + 917504);        // 201,326,592 B

  k_prep_w<<<384, 256, 0, stream>>>(whh, Wp);
  k_gx<<<dim3((B_ * T_) / 64, G_ / 64), 256, 0, stream>>>(x, wih, bih, gx);
  k_gru<<<B_, 512, 0, stream>>>(Wp, gx, bhh, 0);
  k_score<<<(B_ * T_) / 32, 256, 0, stream>>>((const f16*)gx, wvW, wvb, wu, s);
  k_ctx<<<B_, 256, 0, stream>>>((const f16*)gx, s, h2oW, h2ob, out);
}

// Round 3
// 1635.767 us; speedup vs baseline: 1.2218x; 1.2218x over previous
//
#include <hip/hip_runtime.h>

// Att_RNN_GRU: B=128, T=1024, I=128, H=256 (3H=768), A=40
// Phase 1: gx = x @ W_ih^T + b_ih  -> f16 [B*T, 768]  (f16-dot2 tiled GEMM)
// Phase 2: GRU recurrence, 1 block/batch, 768 threads = 1 gate-row/thread.
//          W_hh row register-resident (w[128] packed f16), no cross-lane
//          reduction; h broadcast from LDS; gate exchange via 512-f32 LDS.
//          h_t overwrites gx row (b,t)[0:256].
// Phase 3a: s[b,t] = wu . tanh(wv_W @ out + wv_b)   (outs = gx rows, stride 768)
// Phase 3b: softmax over t, context, out = context @ h2o_W^T + b
//
// Workspace: s @0 (512KB), Wp @524288 (384KB), gx @917504 (192MB) = 202.2MB

#define B_ 128
#define T_ 1024
#define I_ 128
#define H_ 256
#define G_ 768
#define A_ 40

typedef _Float16 f16;
typedef _Float16 f16x2 __attribute__((ext_vector_type(2)));

__device__ __forceinline__ float fdot2(unsigned a, unsigned b, float c){
#if __has_builtin(__builtin_amdgcn_fdot2)
  return __builtin_amdgcn_fdot2(__builtin_bit_cast(f16x2, a),
                                __builtin_bit_cast(f16x2, b), c, false);
#else
  f16x2 av = __builtin_bit_cast(f16x2, a), bv = __builtin_bit_cast(f16x2, b);
  return c + (float)av.x * (float)bv.x + (float)av.y * (float)bv.y;
#endif
}

__device__ __forceinline__ float2 h2f(unsigned u){
  f16x2 h = __builtin_bit_cast(f16x2, u);
  return make_float2((float)h.x, (float)h.y);
}
__device__ __forceinline__ unsigned f2h2(float a, float b){
  f16x2 h; h.x = (f16)a; h.y = (f16)b;
  return __builtin_bit_cast(unsigned, h);
}
__device__ __forceinline__ float sigm_(float x){ return 1.f / (1.f + __expf(-x)); }
__device__ __forceinline__ float tanh_(float x){ return 1.f - 2.f / (__expf(2.f * x) + 1.f); }

// ---------------------------------------------------------------- prep W_hh
// W_hh fp32 [768][256] -> Wp packed f16: Wp[d*768 + r] = (W[r][2d], W[r][2d+1])
// so k_gru thread r loads w[d] = Wp[d*768 + r] coalesced.
__global__ __launch_bounds__(256) void k_prep_w(const float* __restrict__ W,
                                                unsigned* __restrict__ Wp){
  int idx = blockIdx.x * 256 + threadIdx.x;      // 0 .. 98303
  int r = idx >> 7;                              // 0..767
  int d = idx & 127;                             // 0..127
  Wp[(size_t)d * G_ + r] = f2h2(W[r * 256 + 2 * d], W[r * 256 + 2 * d + 1]);
}

// ---------------------------------------------------------------- phase 1
// gx[m][n] = sum_k x[m][k]*W_ih[n][k] + b_ih[n]; f16-dot2 inner loop.
__global__ __launch_bounds__(256) void k_gx(const float* __restrict__ x,
                                            const float* __restrict__ wih,
                                            const float* __restrict__ bih,
                                            unsigned* __restrict__ gx){
  __shared__ __align__(16) unsigned Au[32 * 68];   // [kpair][row], pad 68
  __shared__ __align__(16) unsigned Bu[32 * 68];
  const int tid = threadIdx.x;
  const int m0 = blockIdx.x * 64, n0 = blockIdx.y * 64;
  const int ar = tid >> 4, bc = tid & 15;
  float acc[4][4] = {{0.f}};

  for (int kh = 0; kh < 2; ++kh){
    __syncthreads();
    #pragma unroll
    for (int u = 0; u < 4; ++u){
      int idx = tid + 256 * u;
      int row = idx >> 4;         // 0..63
      int kq  = idx & 15;         // 0..15 (float4 index within 64-k half)
      float4 va = *(const float4*)(x   + (size_t)(m0 + row) * I_ + kh * 64 + kq * 4);
      float4 vb = *(const float4*)(wih + (size_t)(n0 + row) * I_ + kh * 64 + kq * 4);
      Au[(2*kq  ) * 68 + row] = f2h2(va.x, va.y);
      Au[(2*kq+1) * 68 + row] = f2h2(va.z, va.w);
      Bu[(2*kq  ) * 68 + row] = f2h2(vb.x, vb.y);
      Bu[(2*kq+1) * 68 + row] = f2h2(vb.z, vb.w);
    }
    __syncthreads();
    #pragma unroll 8
    for (int kp = 0; kp < 32; ++kp){
      uint4 a4 = *(const uint4*)(Au + kp * 68 + ar * 4);
      uint4 b4 = *(const uint4*)(Bu + kp * 68 + bc * 4);
      acc[0][0]=fdot2(a4.x,b4.x,acc[0][0]); acc[0][1]=fdot2(a4.x,b4.y,acc[0][1]);
      acc[0][2]=fdot2(a4.x,b4.z,acc[0][2]); acc[0][3]=fdot2(a4.x,b4.w,acc[0][3]);
      acc[1][0]=fdot2(a4.y,b4.x,acc[1][0]); acc[1][1]=fdot2(a4.y,b4.y,acc[1][1]);
      acc[1][2]=fdot2(a4.y,b4.z,acc[1][2]); acc[1][3]=fdot2(a4.y,b4.w,acc[1][3]);
      acc[2][0]=fdot2(a4.z,b4.x,acc[2][0]); acc[2][1]=fdot2(a4.z,b4.y,acc[2][1]);
      acc[2][2]=fdot2(a4.z,b4.z,acc[2][2]); acc[2][3]=fdot2(a4.z,b4.w,acc[2][3]);
      acc[3][0]=fdot2(a4.w,b4.x,acc[3][0]); acc[3][1]=fdot2(a4.w,b4.y,acc[3][1]);
      acc[3][2]=fdot2(a4.w,b4.z,acc[3][2]); acc[3][3]=fdot2(a4.w,b4.w,acc[3][3]);
    }
  }

  float bn[4];
  #pragma unroll
  for (int j = 0; j < 4; ++j) bn[j] = bih[n0 + bc * 4 + j];
  #pragma unroll
  for (int i = 0; i < 4; ++i){
    int m = m0 + ar * 4 + i;
    uint2 st;
    st.x = f2h2(acc[i][0] + bn[0], acc[i][1] + bn[1]);
    st.y = f2h2(acc[i][2] + bn[2], acc[i][3] + bn[3]);
    *(uint2*)(gx + (size_t)m * (G_ / 2) + n0 / 2 + bc * 2) = st;
  }
}

// ---------------------------------------------------------------- phase 2
// One block per batch, 768 threads; thread r computes full dot of W_hh row r
// with h (no cross-lane reduction). h lives in LDS as 32 uint4 (broadcast
// reads, conflict-free). Rows 256..767 post (a [+sigm] + bias [+ x]) to GH;
// rows 0..255 do the gate math with full lane activity.
__global__ __launch_bounds__(768, 3) void k_gru(const unsigned* __restrict__ Wp,
                                                unsigned* __restrict__ gx,
                                                const float* __restrict__ bhh){
  __shared__ uint4 Hc4[32];       // h: 256 f16 packed
  __shared__ float GH[512];       // z (pre-sigmoided) & n partials
  const int tid = threadIdx.x;    // gate row r
  const int b = blockIdx.x;

  unsigned w[128];
  #pragma unroll
  for (int d = 0; d < 128; ++d) w[d] = Wp[(size_t)d * G_ + tid];

  const float bias = bhh[tid];
  float hprev = 0.f;
  if (tid < 32) Hc4[tid] = make_uint4(0, 0, 0, 0);

  f16* gxp = (f16*)gx + (size_t)b * T_ * G_;

  // preload x-terms for t=0
  float xcur  = (float)gxp[tid];
  float xncur = (tid < 256) ? (float)gxp[512 + tid] : 0.f;
  __syncthreads();

  for (int t = 0; t < T_; ++t){
    // prefetch next step's x-terms (consumed after barrier; hides HBM latency)
    float xnext = 0.f, xnnext = 0.f;
    if (t + 1 < T_){
      xnext = (float)gxp[(size_t)(t + 1) * G_ + tid];
      if (tid < 256) xnnext = (float)gxp[(size_t)(t + 1) * G_ + 512 + tid];
    }

    // a = W_hh[r] . h   (two chains for ILP; LDS reads are wave-uniform)
    float a0 = 0.f, a1 = 0.f;
    #pragma unroll
    for (int j = 0; j < 32; ++j){
      uint4 hv = Hc4[j];
      a0 = fdot2(w[4*j+0], hv.x, a0); a1 = fdot2(w[4*j+1], hv.y, a1);
      a0 = fdot2(w[4*j+2], hv.z, a0); a1 = fdot2(w[4*j+3], hv.w, a1);
    }
    float a = a0 + a1;

    if (tid >= 512)      GH[tid - 256] = a + bias;                 // n: hn sum
    else if (tid >= 256) GH[tid - 256] = sigm_(a + bias + xcur);   // z: done
    __syncthreads();

    if (tid < 256){
      float rg = sigm_(xcur + a + bias);
      float zg = GH[tid];
      float ng = tanh_(xncur + rg * GH[256 + tid]);
      float h  = (1.f - zg) * ng + zg * hprev;
      hprev = h;
      f16 hh = (f16)h;
      ((f16*)Hc4)[tid] = hh;                      // new h for next step
      gxp[(size_t)t * G_ + tid] = hh;             // overwrite consumed gx row
      xncur = xnnext;
    }
    xcur = xnext;
    __syncthreads();
  }
}

// ---------------------------------------------------------------- phase 3a
// s[m] = sum_a wu[a] * tanh( sum_k outs[m][k]*wv_W[a][k] + wv_b[a] )
// outs = first 256 halfs of each 768-half gx row.
__global__ __launch_bounds__(256) void k_score(const f16* __restrict__ outs,
                                               const float* __restrict__ wvW,
                                               const float* __restrict__ wvb,
                                               const float* __restrict__ wu,
                                               float* __restrict__ s){
  __shared__ uint4 OT[32 * 33];      // 32 rows x 256 halfs, pad 33
  __shared__ float WV[A_ * 260];     // 40 x 256 fp32, pad 260
  const int tid = threadIdx.x;
  const int m0 = blockIdx.x * 32;

  #pragma unroll
  for (int u = 0; u < 4; ++u){
    int idx = tid + 256 * u;         // 0..1023
    int row = idx >> 5, col = idx & 31;
    OT[row * 33 + col] = *(const uint4*)(outs + (size_t)(m0 + row) * G_ + col * 8);
  }
  #pragma unroll
  for (int u = 0; u < 10; ++u){
    int f = tid + 256 * u;           // 0..2559 float4s
    int a = f >> 6, k4 = f & 63;
    float4 v = *(const float4*)(wvW + a * 256 + k4 * 4);
    *(float4*)(WV + a * 260 + k4 * 4) = v;
  }
  __syncthreads();

  const int m = tid >> 3, aq = tid & 7;
  float acc[5] = {0.f, 0.f, 0.f, 0.f, 0.f};
  for (int i = 0; i < 32; ++i){
    uint4 oc = OT[m * 33 + i];
    float2 o01 = h2f(oc.x), o23 = h2f(oc.y), o45 = h2f(oc.z), o67 = h2f(oc.w);
    #pragma unroll
    for (int sa = 0; sa < 5; ++sa){
      int a = aq + sa * 8;
      const float* wr = &WV[a * 260 + i * 8];
      float4 w0 = *(const float4*)wr;
      float4 w1 = *(const float4*)(wr + 4);
      acc[sa] += o01.x*w0.x + o01.y*w0.y + o23.x*w0.z + o23.y*w0.w
               + o45.x*w1.x + o45.y*w1.y + o67.x*w1.z + o67.y*w1.w;
    }
  }
  float sp = 0.f;
  #pragma unroll
  for (int sa = 0; sa < 5; ++sa){
    int a = aq + sa * 8;
    sp += wu[a] * tanh_(acc[sa] + wvb[a]);
  }
  sp += __shfl_xor(sp, 1);
  sp += __shfl_xor(sp, 2);
  sp += __shfl_xor(sp, 4);
  if (aq == 0) s[m0 + m] = sp;
}

// ---------------------------------------------------------------- phase 3b
// softmax over t per batch, context = sum_t alpha*outs, out[b] = context.h2o + b
__global__ __launch_bounds__(256) void k_ctx(const f16* __restrict__ outs,
                                             const float* __restrict__ s,
                                             const float* __restrict__ h2oW,
                                             const float* __restrict__ h2ob,
                                             float* __restrict__ out){
  __shared__ float AL[T_];
  __shared__ float red[8];
  const int tid = threadIdx.x;
  const int b = blockIdx.x;
  const float* sb = s + (size_t)b * T_;

  float v0 = sb[tid], v1 = sb[tid + 256], v2 = sb[tid + 512], v3 = sb[tid + 768];
  float mx = fmaxf(fmaxf(v0, v1), fmaxf(v2, v3));
  #pragma unroll
  for (int msk = 1; msk < 64; msk <<= 1) mx = fmaxf(mx, __shfl_xor(mx, msk));
  if ((tid & 63) == 0) red[tid >> 6] = mx;
  __syncthreads();
  mx = fmaxf(fmaxf(red[0], red[1]), fmaxf(red[2], red[3]));

  float e0 = __expf(v0 - mx), e1 = __expf(v1 - mx), e2 = __expf(v2 - mx), e3 = __expf(v3 - mx);
  float zs = e0 + e1 + e2 + e3;
  #pragma unroll
  for (int msk = 1; msk < 64; msk <<= 1) zs += __shfl_xor(zs, msk);
  if ((tid & 63) == 0) red[4 + (tid >> 6)] = zs;
  __syncthreads();
  float invZ = 1.f / (red[4] + red[5] + red[6] + red[7]);
  AL[tid] = e0 * invZ; AL[tid + 256] = e1 * invZ;
  AL[tid + 512] = e2 * invZ; AL[tid + 768] = e3 * invZ;
  __syncthreads();

  const f16* ob = outs + (size_t)b * T_ * G_;
  float acc = 0.f;
  for (int t = 0; t < T_; t += 4){
    acc += AL[t + 0] * (float)ob[(size_t)(t + 0) * G_ + tid];
    acc += AL[t + 1] * (float)ob[(size_t)(t + 1) * G_ + tid];
    acc += AL[t + 2] * (float)ob[(size_t)(t + 2) * G_ + tid];
    acc += AL[t + 3] * (float)ob[(size_t)(t + 3) * G_ + tid];
  }
  __syncthreads();
  float val = acc * h2oW[tid];
  #pragma unroll
  for (int msk = 1; msk < 64; msk <<= 1) val += __shfl_xor(val, msk);
  if ((tid & 63) == 0) red[tid >> 6] = val;
  __syncthreads();
  if (tid == 0) out[b] = red[0] + red[1] + red[2] + red[3] + h2ob[0];
}

// ---------------------------------------------------------------- launch
extern "C" void kernel_launch(void* const* d_in, const int* in_sizes, int n_in,
                              void* d_out, int out_size, void* d_ws, size_t ws_size,
                              hipStream_t stream){
  const float* x    = (const float*)d_in[0];
  const float* wih  = (const float*)d_in[1];
  const float* whh  = (const float*)d_in[2];
  const float* bih  = (const float*)d_in[3];
  const float* bhh  = (const float*)d_in[4];
  const float* wvW  = (const float*)d_in[5];
  const float* wvb  = (const float*)d_in[6];
  const float* wu   = (const float*)d_in[7];
  const float* h2oW = (const float*)d_in[8];
  const float* h2ob = (const float*)d_in[9];
  float* out = (float*)d_out;

  char* ws = (char*)d_ws;
  float*    s  = (float*)ws;                      //     524,288 B
  unsigned* Wp = (unsigned*)(ws + 524288);        //     393,216 B
  unsigned* gx = (unsigned*)(ws + 917504);        // 201,326,592 B

  k_prep_w<<<384, 256, 0, stream>>>(whh, Wp);
  k_gx<<<dim3((B_ * T_) / 64, G_ / 64), 256, 0, stream>>>(x, wih, bih, gx);
  k_gru<<<B_, 768, 0, stream>>>(Wp, gx, bhh);
  k_score<<<(B_ * T_) / 32, 256, 0, stream>>>((const f16*)gx, wvW, wvb, wu, s);
  k_ctx<<<B_, 256, 0, stream>>>((const f16*)gx, s, h2oW, h2ob, out);
}